// Round 12
// baseline (135.463 us; speedup 1.0000x reference)
//
#include <hip/hip_runtime.h>
#include <hip/hip_bf16.h>

// Problem: B=8, C=DIM=64, H=W=64 -> pooled 32x32 (N=1024 tokens), 16 heads x d=4.
// ws layout (floats): t[524288] | idx[524288 ints] | q[524288] | k[524288] | v[524288]
//                     | o[524288] (normalized attention output, (B,N,64))
// q/k/v layout: (B, H=16, N=1024, D=4) contiguous -> per (b,h) a 4096-float slab.

typedef float    v2f   __attribute__((ext_vector_type(2)));
typedef float    f32x4 __attribute__((ext_vector_type(4)));
typedef _Float16 f16x8 __attribute__((ext_vector_type(8)));

// ---------------- Kernel A: 2x2 maxpool + argmax ----------------
__global__ __launch_bounds__(256) void pool_kernel(const float* __restrict__ x,
                                                   float* __restrict__ t,
                                                   int* __restrict__ idx) {
    int g = blockIdx.x * 256 + threadIdx.x;            // covers 8*64*32*32 = 524288
    int wp = g & 31, hp = (g >> 5) & 31, c = (g >> 10) & 63, b = g >> 16;
    const float* px = x + (((b * 64 + c) * 64 + 2 * hp) * 64 + 2 * wp);
    float2 r0 = *(const float2*)px;
    float2 r1 = *(const float2*)(px + 64);
    float best = r0.x; int bi = 0;                      // first-max semantics (strict >)
    if (r0.y > best) { best = r0.y; bi = 1; }
    if (r1.x > best) { best = r1.x; bi = 2; }
    if (r1.y > best) { best = r1.y; bi = 3; }
    int n = hp * 32 + wp;
    t[(b * 1024 + n) * 64 + c] = best;
    idx[g] = bi;                                        // layout (b,c,hp,wp)
}

// ---------------- Kernel B: qkv = t @ w_qkv, scatter to (B,H,N,4) ----------------
// Each thread owns TWO columns {j, j+96} and 8 rows (halved block LDS reads vs the
// 1-column version; <=2-way broadcast aliasing on trow reads is free).
__global__ __launch_bounds__(192) void qkv_kernel(const float* __restrict__ t,
                                                  const float* __restrict__ w_qkv,
                                                  float* __restrict__ q,
                                                  float* __restrict__ k,
                                                  float* __restrict__ v) {
    __shared__ float trow[16 * 64];                     // 16 token rows
    int tid = threadIdx.x;                              // 0..191
    int row0 = blockIdx.x * 16;
    for (int i = tid; i < 1024; i += 192) trow[i] = t[row0 * 64 + i];
    int j  = tid % 96;                                  // my column pair {j, j+96}
    int rh = tid / 96;                                  // my row half (8 rows)
    float wc0[64], wc1[64];                             // two w_qkv columns in regs
    #pragma unroll
    for (int c = 0; c < 64; c++) {
        wc0[c] = w_qkv[c * 192 + j];
        wc1[c] = w_qkv[c * 192 + j + 96];
    }
    __syncthreads();
    int s0 = j >> 6, h0 = (j >> 2) & 15, d0 = j & 3;
    int j1 = j + 96;
    int s1 = j1 >> 6, h1 = (j1 >> 2) & 15, d1 = j1 & 3;
    float* dst0 = (s0 == 0) ? q : (s0 == 1) ? k : v;
    float* dst1 = (s1 == 0) ? q : (s1 == 1) ? k : v;
    for (int r = 0; r < 8; r++) {
        int row = rh * 8 + r;
        const float4* tr = (const float4*)&trow[row * 64];
        float a0 = 0.f, a1 = 0.f;
        #pragma unroll
        for (int c4 = 0; c4 < 16; c4++) {
            float4 tv = tr[c4];                         // <=2-way LDS broadcast: free
            a0 += tv.x * wc0[c4 * 4] + tv.y * wc0[c4 * 4 + 1]
                + tv.z * wc0[c4 * 4 + 2] + tv.w * wc0[c4 * 4 + 3];
            a1 += tv.x * wc1[c4 * 4] + tv.y * wc1[c4 * 4 + 1]
                + tv.z * wc1[c4 * 4 + 2] + tv.w * wc1[c4 * 4 + 3];
        }
        int ng = row0 + row, b = ng >> 10, n = ng & 1023;
        dst0[((b * 16 + h0) * 1024 + n) * 4 + d0] = a0;
        dst1[((b * 16 + h1) * 1024 + n) * 4 + d1] = a1;
    }
}

// ---------------- Kernel C: MFMA attention, Markidis-exact S, LDS epilogue ----------
// R11 post-mortem: attn ~30 us; binding resource is the per-CU LDS pipe -- each
// b128 broadcast read delivers only 256 B of unique payload (4 quads alias).
// This version amortizes each K/V tile read over 64 rows/wave (strips 2->4),
// halving per-CU LDS reads; grid 1024->512 (2 blocks/CU), per-wave ILP doubles
// (4 independent strip chains). MFMA scheme + epilogue unchanged from R10/R11:
//   A: quad0={qh|qh}, quad1={ql|ql}, quads2-3=0
//   B: quads0-1={kh[0..3]|kl[0..3]}, quads2-3=0  => S=(qh+ql)(kh+kl), ~2^-22 exact.
// grid = 128 bh * 4 row-blocks of 256 rows; block = 4 waves, wave = 4 strips of 16.
__global__ __launch_bounds__(256) void attn_kernel(const float* __restrict__ q,
                                                   const float* __restrict__ k,
                                                   const float* __restrict__ v,
                                                   float* __restrict__ o) {
    __shared__ __align__(16) unsigned char smem[32768];
    f16x8*  Kh2  = (f16x8*)smem;                        // [0,16384): 1024 keys {hi4|lo4}
    float4* Vs   = (float4*)(smem + 16384);             // [16384,32768): 1024 vals fp32
    float4* red4 = (float4*)smem;                       // epilogue alias [0,16384)
    float*  redl = (float*)(smem + 16384);              // epilogue alias [16384,20480)
    int bh = blockIdx.x >> 2;
    int row0 = (blockIdx.x & 3) * 256;
    int tid = threadIdx.x;
    const float4* kp4 = (const float4*)(k + bh * 4096);
    const float4* vp4 = (const float4*)(v + bh * 4096);
    #pragma unroll
    for (int i = 0; i < 4; i++) {                       // stage K (hi/lo f16) + V (fp32)
        int ix = i * 256 + tid;
        float4 kf = kp4[ix];
        f16x8 kk;
        kk[0] = (_Float16)kf.x; kk[4] = (_Float16)(kf.x - (float)kk[0]);
        kk[1] = (_Float16)kf.y; kk[5] = (_Float16)(kf.y - (float)kk[1]);
        kk[2] = (_Float16)kf.z; kk[6] = (_Float16)(kf.z - (float)kk[2]);
        kk[3] = (_Float16)kf.w; kk[7] = (_Float16)(kf.w - (float)kk[3]);
        Kh2[ix] = kk;
        Vs[ix] = vp4[ix];
    }
    int w = tid >> 6, lane = tid & 63;
    int c = lane & 15, quad = lane >> 4;
    const float C1 = 0.5f * 1.44269504088896f;          // scale * log2(e), folded into Q
    const float4* qp4 = (const float4*)(q + bh * 4096);
    f16x8 afrag[4];
    #pragma unroll
    for (int s = 0; s < 4; s++) {                       // A-frags for my 4 row strips
        int rowg = row0 + w * 64 + s * 16 + c;
        float4 qv = qp4[rowg];
        float qx = qv.x * C1, qy = qv.y * C1, qz = qv.z * C1, qw = qv.w * C1;
        _Float16 hx = (_Float16)qx, hy = (_Float16)qy,
                 hz = (_Float16)qz, hw = (_Float16)qw;
        _Float16 gx = (_Float16)(qx - (float)hx), gy = (_Float16)(qy - (float)hy),
                 gz = (_Float16)(qz - (float)hz), gw = (_Float16)(qw - (float)hw);
        f16x8 a = {};
        if (quad == 0) {                                // hi half, duplicated j0-3/j4-7
            a[0] = hx; a[1] = hy; a[2] = hz; a[3] = hw;
            a[4] = hx; a[5] = hy; a[6] = hz; a[7] = hw;
        } else if (quad == 1) {                         // lo half, duplicated
            a[0] = gx; a[1] = gy; a[2] = gz; a[3] = gw;
            a[4] = gx; a[5] = gy; a[6] = gz; a[7] = gw;
        }
        afrag[s] = a;
    }
    bool okb = (quad < 2);
    __syncthreads();
    v2f ax2[4][2], ay2[4][2], az2[4][2], aw2[4][2], l2[4][2];
    #pragma unroll
    for (int s = 0; s < 4; s++)
        #pragma unroll
        for (int p = 0; p < 2; p++) {
            ax2[s][p] = (v2f)(0.f); ay2[s][p] = (v2f)(0.f);
            az2[s][p] = (v2f)(0.f); aw2[s][p] = (v2f)(0.f);
            l2[s][p]  = (v2f)(0.f);
        }
    const f16x8 bz = {};
    #pragma unroll 2
    for (int t = 0; t < 64; t++) {                      // 16-key tiles
        f16x8 kv8 = Kh2[t * 16 + c];                    // ds_read_b128 (broadcast)
        float4 vv = Vs[t * 16 + c];                     // ds_read_b128 (broadcast)
        f16x8 b = okb ? kv8 : bz;                       // quads 2-3 contribute zero
        v2f vx2 = (v2f){vv.x, vv.x}, vy2 = (v2f){vv.y, vv.y};
        v2f vz2 = (v2f){vv.z, vv.z}, vw2 = (v2f){vv.w, vv.w};
        #pragma unroll
        for (int s = 0; s < 4; s++) {
            f32x4 S = __builtin_amdgcn_mfma_f32_16x16x32_f16(afrag[s], b,
                                                             (f32x4)(0.f), 0, 0, 0);
            float p0 = __builtin_amdgcn_exp2f(S[0]);    // bare v_exp_f32 (trans pipe)
            float p1 = __builtin_amdgcn_exp2f(S[1]);
            float p2 = __builtin_amdgcn_exp2f(S[2]);
            float p3 = __builtin_amdgcn_exp2f(S[3]);
            v2f p01 = (v2f){p0, p1}, p23 = (v2f){p2, p3};
            l2[s][0] += p01; l2[s][1] += p23;           // v_pk_add_f32
            ax2[s][0] = __builtin_elementwise_fma(p01, vx2, ax2[s][0]);
            ax2[s][1] = __builtin_elementwise_fma(p23, vx2, ax2[s][1]);
            ay2[s][0] = __builtin_elementwise_fma(p01, vy2, ay2[s][0]);
            ay2[s][1] = __builtin_elementwise_fma(p23, vy2, ay2[s][1]);
            az2[s][0] = __builtin_elementwise_fma(p01, vz2, az2[s][0]);
            az2[s][1] = __builtin_elementwise_fma(p23, vz2, az2[s][1]);
            aw2[s][0] = __builtin_elementwise_fma(p01, vw2, aw2[s][0]);
            aw2[s][1] = __builtin_elementwise_fma(p23, vw2, aw2[s][1]);
        }
    }
    // LDS-reduction epilogue: per strip, each lane dumps its 4 rows x 1 key-column
    // partials; lanes 0..15 of each wave sum the 16 columns for one row each and
    // store the normalized o row.
    int b0 = bh >> 4, h = bh & 15;
    #pragma unroll
    for (int s = 0; s < 4; s++) {
        __syncthreads();                                // K/V reads (or prior strip) done
        #pragma unroll
        for (int r = 0; r < 4; r++) {
            int p = r >> 1; int hi = r & 1;
            int ix = w * 256 + (quad * 4 + r) * 16 + c; // per-wave 256-entry area
            float4 n4 = { hi ? ax2[s][p].y : ax2[s][p].x,
                          hi ? ay2[s][p].y : ay2[s][p].x,
                          hi ? az2[s][p].y : az2[s][p].x,
                          hi ? aw2[s][p].y : aw2[s][p].x };
            red4[ix] = n4;
            redl[ix] = hi ? l2[s][p].y : l2[s][p].x;
        }
        __syncthreads();
        if (lane < 16) {                                // one row per lane
            float4 acc = {0.f, 0.f, 0.f, 0.f}; float lacc = 0.f;
            #pragma unroll
            for (int cc = 0; cc < 16; cc++) {
                float4 t4 = red4[w * 256 + lane * 16 + cc];
                acc.x += t4.x; acc.y += t4.y; acc.z += t4.z; acc.w += t4.w;
                lacc += redl[w * 256 + lane * 16 + cc];
            }
            float rl = 1.f / lacc;
            int rowg = row0 + w * 64 + s * 16 + lane;
            float4 res = { acc.x * rl, acc.y * rl, acc.z * rl, acc.w * rl };
            *(float4*)&o[(b0 * 1024 + rowg) * 64 + h * 4] = res;
        }
    }
}

// ---------------- Kernel D: o @ w_proj + BN + max-unpool scatter ----------------
// Channels come in two groups of 4 consecutive c so ws is read as float4 (b128,
// 2 distinct addresses/wave = free broadcast).
__global__ __launch_bounds__(256) void proj_kernel(const float* __restrict__ o,
                                                   const float* __restrict__ w_proj,
                                                   const float* __restrict__ gamma,
                                                   const float* __restrict__ beta,
                                                   const float* __restrict__ mean,
                                                   const float* __restrict__ var,
                                                   const int* __restrict__ idx,
                                                   float* __restrict__ out) {
    __shared__ float ws[64 * 64];                       // w_proj
    int b = blockIdx.x >> 5, hp = blockIdx.x & 31;
    int tid = threadIdx.x;
    for (int i = tid; i < 4096; i += 256) ws[i] = w_proj[i];
    int wp = tid & 31, cg = tid >> 5;                   // 8 c-groups x 32 wp
    float oreg[64];                                     // my o row in registers
    const float* orow = o + (b * 1024 + hp * 32 + wp) * 64;
    #pragma unroll
    for (int a4 = 0; a4 < 16; a4++) {
        float4 t4 = ((const float4*)orow)[a4];
        oreg[a4 * 4] = t4.x; oreg[a4 * 4 + 1] = t4.y;
        oreg[a4 * 4 + 2] = t4.z; oreg[a4 * 4 + 3] = t4.w;
    }
    __syncthreads();
    #pragma unroll
    for (int g = 0; g < 2; g++) {
        int c0 = cg * 8 + g * 4;                        // 4 consecutive channels
        float4 acc = {0.f, 0.f, 0.f, 0.f};
        #pragma unroll
        for (int a = 0; a < 64; a++) {
            float4 wv = *(const float4*)&ws[a * 64 + c0];   // b128, 2-addr broadcast
            acc.x += oreg[a] * wv.x; acc.y += oreg[a] * wv.y;
            acc.z += oreg[a] * wv.z; acc.w += oreg[a] * wv.w;
        }
        float accs[4] = { acc.x, acc.y, acc.z, acc.w };
        #pragma unroll
        for (int i = 0; i < 4; i++) {
            int c = c0 + i;
            float inv = gamma[c] * rsqrtf(var[c] + 1e-5f);
            float val = accs[i] * inv + (beta[c] - mean[c] * inv);
            int id = idx[((b * 64 + c) * 32 + hp) * 32 + wp];
            int base = ((b * 64 + c) * 64 + 2 * hp) * 64 + 2 * wp;
            float2 r0 = { id == 0 ? val : 0.f, id == 1 ? val : 0.f };
            float2 r1 = { id == 2 ? val : 0.f, id == 3 ? val : 0.f };
            *(float2*)&out[base] = r0;                  // row 2hp,   cols 2wp..2wp+1
            *(float2*)&out[base + 64] = r1;             // row 2hp+1
        }
    }
}

extern "C" void kernel_launch(void* const* d_in, const int* in_sizes, int n_in,
                              void* d_out, int out_size, void* d_ws, size_t ws_size,
                              hipStream_t stream) {
    const float* x      = (const float*)d_in[0];
    const float* w_qkv  = (const float*)d_in[1];
    const float* w_proj = (const float*)d_in[2];
    const float* gamma  = (const float*)d_in[3];
    const float* beta   = (const float*)d_in[4];
    const float* bn_mean= (const float*)d_in[5];
    const float* bn_var = (const float*)d_in[6];
    float* out = (float*)d_out;

    const int SEG = 524288;                             // 8*1024*64
    float* ws = (float*)d_ws;
    float* t   = ws;
    int*   idx = (int*)(ws + SEG);
    float* q   = ws + 2 * SEG;
    float* k   = ws + 3 * SEG;
    float* v   = ws + 4 * SEG;
    float* o   = ws + 5 * SEG;

    pool_kernel<<<2048, 256, 0, stream>>>(x, t, idx);
    qkv_kernel<<<512, 192, 0, stream>>>(t, w_qkv, q, k, v);
    attn_kernel<<<512, 256, 0, stream>>>(q, k, v, o);
    proj_kernel<<<256, 256, 0, stream>>>(o, w_proj, gamma, beta, bn_mean, bn_var, idx, out);
}

// Round 15
// 129.811 us; speedup vs baseline: 1.0435x; 1.0435x over previous
//
#include <hip/hip_runtime.h>
#include <hip/hip_bf16.h>

// Problem: B=8, C=DIM=64, H=W=64 -> pooled 32x32 (N=1024 tokens), 16 heads x d=4.
// ws layout (floats): t[524288] | idx[524288 ints] | q[524288] | k[524288] | v[524288]
//                     | o[524288] (normalized attention output, (B,N,64))
// q/k/v layout: (B, H=16, N=1024, D=4) contiguous -> per (b,h) a 4096-float slab.

typedef float    f32x4 __attribute__((ext_vector_type(4)));
typedef _Float16 f16x8 __attribute__((ext_vector_type(8)));
typedef unsigned int uint32_tt;

// ---------------- Kernel A: 2x2 maxpool + argmax ----------------
__global__ __launch_bounds__(256) void pool_kernel(const float* __restrict__ x,
                                                   float* __restrict__ t,
                                                   int* __restrict__ idx) {
    int g = blockIdx.x * 256 + threadIdx.x;            // covers 8*64*32*32 = 524288
    int wp = g & 31, hp = (g >> 5) & 31, c = (g >> 10) & 63, b = g >> 16;
    const float* px = x + (((b * 64 + c) * 64 + 2 * hp) * 64 + 2 * wp);
    float2 r0 = *(const float2*)px;
    float2 r1 = *(const float2*)(px + 64);
    float best = r0.x; int bi = 0;                      // first-max semantics (strict >)
    if (r0.y > best) { best = r0.y; bi = 1; }
    if (r1.x > best) { best = r1.x; bi = 2; }
    if (r1.y > best) { best = r1.y; bi = 3; }
    int n = hp * 32 + wp;
    t[(b * 1024 + n) * 64 + c] = best;
    idx[g] = bi;                                        // layout (b,c,hp,wp)
}

// ---------------- Kernel B: qkv = t @ w_qkv, scatter to (B,H,N,4) ----------------
__global__ __launch_bounds__(192) void qkv_kernel(const float* __restrict__ t,
                                                  const float* __restrict__ w_qkv,
                                                  float* __restrict__ q,
                                                  float* __restrict__ k,
                                                  float* __restrict__ v) {
    __shared__ float trow[16 * 64];                     // 16 token rows
    int tid = threadIdx.x;                              // 0..191
    int row0 = blockIdx.x * 16;
    for (int i = tid; i < 1024; i += 192) trow[i] = t[row0 * 64 + i];
    int j  = tid % 96;                                  // my column pair {j, j+96}
    int rh = tid / 96;                                  // my row half (8 rows)
    float wc0[64], wc1[64];
    #pragma unroll
    for (int c = 0; c < 64; c++) {
        wc0[c] = w_qkv[c * 192 + j];
        wc1[c] = w_qkv[c * 192 + j + 96];
    }
    __syncthreads();
    int s0 = j >> 6, h0 = (j >> 2) & 15, d0 = j & 3;
    int j1 = j + 96;
    int s1 = j1 >> 6, h1 = (j1 >> 2) & 15, d1 = j1 & 3;
    float* dst0 = (s0 == 0) ? q : (s0 == 1) ? k : v;
    float* dst1 = (s1 == 0) ? q : (s1 == 1) ? k : v;
    for (int r = 0; r < 8; r++) {
        int row = rh * 8 + r;
        const float4* tr = (const float4*)&trow[row * 64];
        float a0 = 0.f, a1 = 0.f;
        #pragma unroll
        for (int c4 = 0; c4 < 16; c4++) {
            float4 tv = tr[c4];                         // <=2-way LDS broadcast: free
            a0 += tv.x * wc0[c4 * 4] + tv.y * wc0[c4 * 4 + 1]
                + tv.z * wc0[c4 * 4 + 2] + tv.w * wc0[c4 * 4 + 3];
            a1 += tv.x * wc1[c4 * 4] + tv.y * wc1[c4 * 4 + 1]
                + tv.z * wc1[c4 * 4 + 2] + tv.w * wc1[c4 * 4 + 3];
        }
        int ng = row0 + row, b = ng >> 10, n = ng & 1023;
        dst0[((b * 16 + h0) * 1024 + n) * 4 + d0] = a0;
        dst1[((b * 16 + h1) * 1024 + n) * 4 + d1] = a1;
    }
}

// ---------------- Kernel C: dual-MFMA attention (S^T and O^T both on matrix core) ---
// R14 post-mortem: NaN from f16 overflow of P (p up to ~2^20 > f16 max 2^16).
// Fix: uniform exponent shift p = exp2(S - 14); the 2^-14 scales numerator and
// ones-row denominator identically, cancelling in O/l. Max plausible p = 2^6,
// min row-max p ~ 2^-10 (normal f16). Everything else unchanged from R14:
//  MFMA1: S^T = K x Q^T.  A = raw {kh0..3,kl0..3} f16x8 (lane m=key);
//         B = Q Markidis (quad0={qh|qh}, quad1={ql|ql}) -> S=(kh+kl)(qh+ql) exact.
//         C: lane(c=query, quad) holds keys quad*4+reg.  [same-k pairing: R10-proven]
//  MFMA2: O^T = V^T x P^T.  k-slots pair as s=key*2+part.  A = one ds_read_b128 of
//         transposed V pre-split {vh|vl} (lane m=dim, clamped m>=5 -> ones-row);
//         row m=4 = {1,0,...} so the MFMA also produces l = sum(ph).
//         B = P as f16 (v_cvt_f16_f32) in even slots; key map quad*4+(j>>1) matches
//         MFMA1's C exactly.  O accumulates in C-regs across all 64 tiles.
// Epilogue: quad1 passes l to quad0 via 1KB LDS (one barrier); quad0 stores rows.
// grid = 128 bh * 4 row-blocks of 256; block = 4 waves, wave = 4 strips of 16 rows.
__global__ __launch_bounds__(256) void attn_kernel(const float* __restrict__ q,
                                                   const float* __restrict__ k,
                                                   const float* __restrict__ v,
                                                   float* __restrict__ o) {
    __shared__ __align__(16) unsigned char smem[38080];
    f16x8*     Kh2 = (f16x8*)smem;                      // [0,16384): 1024 keys {hi4|lo4}
    uint32_tt* VT  = (uint32_tt*)(smem + 16384);        // [16384,37024): 5 rows x 1032
    float*     lsc = (float*)(smem + 37024);            // [37024,38048): l exchange
    int bh = blockIdx.x >> 2;
    int row0 = (blockIdx.x & 3) * 256;
    int tid = threadIdx.x;
    const float4* kp4 = (const float4*)(k + bh * 4096);
    const float4* vp4 = (const float4*)(v + bh * 4096);
    #pragma unroll
    for (int i = 0; i < 4; i++) {                       // stage K and V^T (hi/lo f16)
        int key = i * 256 + tid;
        float4 kf = kp4[key];
        f16x8 kk;
        kk[0] = (_Float16)kf.x; kk[4] = (_Float16)(kf.x - (float)kk[0]);
        kk[1] = (_Float16)kf.y; kk[5] = (_Float16)(kf.y - (float)kk[1]);
        kk[2] = (_Float16)kf.z; kk[6] = (_Float16)(kf.z - (float)kk[2]);
        kk[3] = (_Float16)kf.w; kk[7] = (_Float16)(kf.w - (float)kk[3]);
        Kh2[key] = kk;
        float4 vf = vp4[key];
        float vd[4] = { vf.x, vf.y, vf.z, vf.w };
        #pragma unroll
        for (int d = 0; d < 4; d++) {
            _Float16 h = (_Float16)vd[d];
            _Float16 l = (_Float16)(vd[d] - (float)h);
            uint32_tt hi = (uint32_tt)__builtin_bit_cast(unsigned short, l);
            uint32_tt lo = (uint32_tt)__builtin_bit_cast(unsigned short, h);
            VT[d * 1032 + key] = lo | (hi << 16);       // {vh | vl}
        }
        VT[4 * 1032 + key] = 0x00003C00u;               // ones row: {1.0h | 0}
    }
    int w = tid >> 6, lane = tid & 63;
    int c = lane & 15, quad = lane >> 4;
    int mv = (c < 5) ? c : 4;                           // clamp -> broadcast ones-row
    const float C1 = 0.5f * 1.44269504088896f;          // scale*log2(e), folded into Q
    const float4* qp4 = (const float4*)(q + bh * 4096);
    f16x8 bq[4];
    #pragma unroll
    for (int s = 0; s < 4; s++) {                       // Q Markidis B-frags (4 strips)
        int rowg = row0 + w * 64 + s * 16 + c;
        float4 qv = qp4[rowg];
        float qx = qv.x * C1, qy = qv.y * C1, qz = qv.z * C1, qw = qv.w * C1;
        _Float16 hx = (_Float16)qx, hy = (_Float16)qy,
                 hz = (_Float16)qz, hw = (_Float16)qw;
        _Float16 gx = (_Float16)(qx - (float)hx), gy = (_Float16)(qy - (float)hy),
                 gz = (_Float16)(qz - (float)hz), gw = (_Float16)(qw - (float)hw);
        f16x8 a = {};
        if (quad == 0) {
            a[0] = hx; a[1] = hy; a[2] = hz; a[3] = hw;
            a[4] = hx; a[5] = hy; a[6] = hz; a[7] = hw;
        } else if (quad == 1) {
            a[0] = gx; a[1] = gy; a[2] = gz; a[3] = gw;
            a[4] = gx; a[5] = gy; a[6] = gz; a[7] = gw;
        }
        bq[s] = a;
    }
    __syncthreads();
    f32x4 acc[4];
    #pragma unroll
    for (int s = 0; s < 4; s++) acc[s] = (f32x4)(0.f);
    #pragma unroll 2
    for (int t = 0; t < 64; t++) {                      // 16-key tiles
        f16x8 ka = Kh2[t * 16 + c];                     // ds_read_b128 (2-way alias: free)
        const uint32_tt* vp = &VT[mv * 1032 + t * 16 + quad * 4];
        uint4 vr = *(const uint4*)vp;                   // ds_read_b128: V^T A-frag raw
        f16x8 va = __builtin_bit_cast(f16x8, vr);
        #pragma unroll
        for (int s = 0; s < 4; s++) {
            f32x4 S = __builtin_amdgcn_mfma_f32_16x16x32_f16(ka, bq[s],
                                                             (f32x4)(0.f), 0, 0, 0);
            float p0 = __builtin_amdgcn_exp2f(S[0] - 14.f);  // shift keeps P in f16
            float p1 = __builtin_amdgcn_exp2f(S[1] - 14.f);  // range; cancels in O/l
            float p2 = __builtin_amdgcn_exp2f(S[2] - 14.f);
            float p3 = __builtin_amdgcn_exp2f(S[3] - 14.f);
            f16x8 pb = {};                              // {ph, 0} per key slot
            pb[0] = (_Float16)p0;                       // v_cvt_f16_f32 (RTN)
            pb[2] = (_Float16)p1;
            pb[4] = (_Float16)p2;
            pb[6] = (_Float16)p3;
            acc[s] = __builtin_amdgcn_mfma_f32_16x16x32_f16(va, pb, acc[s], 0, 0, 0);
        }
    }
    // Epilogue: quad1 reg0 holds l (row 4 = ones-row); quad0 regs 0-3 hold O dims.
    if (quad == 1) {
        #pragma unroll
        for (int s = 0; s < 4; s++) lsc[w * 64 + s * 16 + c] = acc[s][0];
    }
    __syncthreads();
    if (quad == 0) {
        int b0 = bh >> 4, h = bh & 15;
        #pragma unroll
        for (int s = 0; s < 4; s++) {
            float rl = 1.f / lsc[w * 64 + s * 16 + c];
            int rowg = row0 + w * 64 + s * 16 + c;
            float4 res = { acc[s][0] * rl, acc[s][1] * rl,
                           acc[s][2] * rl, acc[s][3] * rl };
            *(float4*)&o[(b0 * 1024 + rowg) * 64 + h * 4] = res;
        }
    }
}

// ---------------- Kernel D: o @ w_proj + BN + max-unpool scatter ----------------
__global__ __launch_bounds__(256) void proj_kernel(const float* __restrict__ o,
                                                   const float* __restrict__ w_proj,
                                                   const float* __restrict__ gamma,
                                                   const float* __restrict__ beta,
                                                   const float* __restrict__ mean,
                                                   const float* __restrict__ var,
                                                   const int* __restrict__ idx,
                                                   float* __restrict__ out) {
    __shared__ float ws[64 * 64];                       // w_proj
    int b = blockIdx.x >> 5, hp = blockIdx.x & 31;
    int tid = threadIdx.x;
    for (int i = tid; i < 4096; i += 256) ws[i] = w_proj[i];
    int wp = tid & 31, cg = tid >> 5;                   // 8 c-groups x 32 wp
    float oreg[64];                                     // my o row in registers
    const float* orow = o + (b * 1024 + hp * 32 + wp) * 64;
    #pragma unroll
    for (int a4 = 0; a4 < 16; a4++) {
        float4 t4 = ((const float4*)orow)[a4];
        oreg[a4 * 4] = t4.x; oreg[a4 * 4 + 1] = t4.y;
        oreg[a4 * 4 + 2] = t4.z; oreg[a4 * 4 + 3] = t4.w;
    }
    __syncthreads();
    #pragma unroll
    for (int g = 0; g < 2; g++) {
        int c0 = cg * 8 + g * 4;                        // 4 consecutive channels
        float4 acc = {0.f, 0.f, 0.f, 0.f};
        #pragma unroll
        for (int a = 0; a < 64; a++) {
            float4 wv = *(const float4*)&ws[a * 64 + c0];   // b128, 2-addr broadcast
            acc.x += oreg[a] * wv.x; acc.y += oreg[a] * wv.y;
            acc.z += oreg[a] * wv.z; acc.w += oreg[a] * wv.w;
        }
        float accs[4] = { acc.x, acc.y, acc.z, acc.w };
        #pragma unroll
        for (int i = 0; i < 4; i++) {
            int c = c0 + i;
            float inv = gamma[c] * rsqrtf(var[c] + 1e-5f);
            float val = accs[i] * inv + (beta[c] - mean[c] * inv);
            int id = idx[((b * 64 + c) * 32 + hp) * 32 + wp];
            int base = ((b * 64 + c) * 64 + 2 * hp) * 64 + 2 * wp;
            float2 r0 = { id == 0 ? val : 0.f, id == 1 ? val : 0.f };
            float2 r1 = { id == 2 ? val : 0.f, id == 3 ? val : 0.f };
            *(float2*)&out[base] = r0;                  // row 2hp,   cols 2wp..2wp+1
            *(float2*)&out[base + 64] = r1;             // row 2hp+1
        }
    }
}

extern "C" void kernel_launch(void* const* d_in, const int* in_sizes, int n_in,
                              void* d_out, int out_size, void* d_ws, size_t ws_size,
                              hipStream_t stream) {
    const float* x      = (const float*)d_in[0];
    const float* w_qkv  = (const float*)d_in[1];
    const float* w_proj = (const float*)d_in[2];
    const float* gamma  = (const float*)d_in[3];
    const float* beta   = (const float*)d_in[4];
    const float* bn_mean= (const float*)d_in[5];
    const float* bn_var = (const float*)d_in[6];
    float* out = (float*)d_out;

    const int SEG = 524288;                             // 8*1024*64
    float* ws = (float*)d_ws;
    float* t   = ws;
    int*   idx = (int*)(ws + SEG);
    float* q   = ws + 2 * SEG;
    float* k   = ws + 3 * SEG;
    float* v   = ws + 4 * SEG;
    float* o   = ws + 5 * SEG;

    pool_kernel<<<2048, 256, 0, stream>>>(x, t, idx);
    qkv_kernel<<<512, 192, 0, stream>>>(t, w_qkv, q, k, v);
    attn_kernel<<<512, 256, 0, stream>>>(q, k, v, o);
    proj_kernel<<<256, 256, 0, stream>>>(o, w_proj, gamma, beta, bn_mean, bn_var, idx, out);
}

// Round 16
// 123.706 us; speedup vs baseline: 1.0950x; 1.0494x over previous
//
#include <hip/hip_runtime.h>
#include <hip/hip_bf16.h>

// Problem: B=8, C=DIM=64, H=W=64 -> pooled 32x32 (N=1024 tokens), 16 heads x d=4.
// ws layout (floats): t[524288] | idx[524288 ints] | q[524288] | k[524288] | v[524288]
//                     | o[524288] (normalized attention output, (B,N,64))
// q/k/v layout: (B, H=16, N=1024, D=4) contiguous -> per (b,h) a 4096-float slab.

typedef float    f32x4 __attribute__((ext_vector_type(4)));
typedef _Float16 f16x8 __attribute__((ext_vector_type(8)));
typedef unsigned int uint32_tt;

// ---------------- Kernel A: 2x2 maxpool + argmax ----------------
__global__ __launch_bounds__(256) void pool_kernel(const float* __restrict__ x,
                                                   float* __restrict__ t,
                                                   int* __restrict__ idx) {
    int g = blockIdx.x * 256 + threadIdx.x;            // covers 8*64*32*32 = 524288
    int wp = g & 31, hp = (g >> 5) & 31, c = (g >> 10) & 63, b = g >> 16;
    const float* px = x + (((b * 64 + c) * 64 + 2 * hp) * 64 + 2 * wp);
    float2 r0 = *(const float2*)px;
    float2 r1 = *(const float2*)(px + 64);
    float best = r0.x; int bi = 0;                      // first-max semantics (strict >)
    if (r0.y > best) { best = r0.y; bi = 1; }
    if (r1.x > best) { best = r1.x; bi = 2; }
    if (r1.y > best) { best = r1.y; bi = 3; }
    int n = hp * 32 + wp;
    t[(b * 1024 + n) * 64 + c] = best;
    idx[g] = bi;                                        // layout (b,c,hp,wp)
}

// ---------------- Kernel B: qkv = t @ w_qkv, scatter to (B,H,N,4) ----------------
__global__ __launch_bounds__(192) void qkv_kernel(const float* __restrict__ t,
                                                  const float* __restrict__ w_qkv,
                                                  float* __restrict__ q,
                                                  float* __restrict__ k,
                                                  float* __restrict__ v) {
    __shared__ float trow[16 * 64];                     // 16 token rows
    int tid = threadIdx.x;                              // 0..191
    int row0 = blockIdx.x * 16;
    for (int i = tid; i < 1024; i += 192) trow[i] = t[row0 * 64 + i];
    int j  = tid % 96;                                  // my column pair {j, j+96}
    int rh = tid / 96;                                  // my row half (8 rows)
    float wc0[64], wc1[64];
    #pragma unroll
    for (int c = 0; c < 64; c++) {
        wc0[c] = w_qkv[c * 192 + j];
        wc1[c] = w_qkv[c * 192 + j + 96];
    }
    __syncthreads();
    int s0 = j >> 6, h0 = (j >> 2) & 15, d0 = j & 3;
    int j1 = j + 96;
    int s1 = j1 >> 6, h1 = (j1 >> 2) & 15, d1 = j1 & 3;
    float* dst0 = (s0 == 0) ? q : (s0 == 1) ? k : v;
    float* dst1 = (s1 == 0) ? q : (s1 == 1) ? k : v;
    for (int r = 0; r < 8; r++) {
        int row = rh * 8 + r;
        const float4* tr = (const float4*)&trow[row * 64];
        float a0 = 0.f, a1 = 0.f;
        #pragma unroll
        for (int c4 = 0; c4 < 16; c4++) {
            float4 tv = tr[c4];                         // <=2-way LDS broadcast: free
            a0 += tv.x * wc0[c4 * 4] + tv.y * wc0[c4 * 4 + 1]
                + tv.z * wc0[c4 * 4 + 2] + tv.w * wc0[c4 * 4 + 3];
            a1 += tv.x * wc1[c4 * 4] + tv.y * wc1[c4 * 4 + 1]
                + tv.z * wc1[c4 * 4 + 2] + tv.w * wc1[c4 * 4 + 3];
        }
        int ng = row0 + row, b = ng >> 10, n = ng & 1023;
        dst0[((b * 16 + h0) * 1024 + n) * 4 + d0] = a0;
        dst1[((b * 16 + h1) * 1024 + n) * 4 + d1] = a1;
    }
}

// ---------------- Kernel C: dual-MFMA attention, 32-key tile-pairs ------------------
// R15 post-mortem: MFMA2's odd k-slots multiplied V-residuals against ZERO P slots
// (inert), so half of MFMA2+VT traffic was wasted. This version stores V as plain
// f16, one slot per key, in a PERMUTED layout so one MFMA2 consumes 32 keys:
//   slot j of quad q  <->  key kappa(q,j) = 32T + (j<4 ? q*4+j : 16 + q*4 + (j-4))
// which is exactly the key set two consecutive MFMA1 C-frags give this lane
// (C row = quad*4+reg, m89-verified). pb[0..3] <- S-tile 2T, pb[4..7] <- S-tile 2T+1.
// Ones-row m=4 (all 8 slots 1.0h) makes MFMA2 emit l = sum(p). P via RTN f16 cvt
// with exp2(S-14) shift (cancels in O/l; keeps P in f16 range -- R15-proven).
// MFMA1 (Q/K Markidis, fp32-exact), grid, strips, epilogue: frozen from R15.
// grid = 128 bh * 4 row-blocks of 256; block = 4 waves, wave = 4 strips of 16 rows.
__global__ __launch_bounds__(256) void attn_kernel(const float* __restrict__ q,
                                                   const float* __restrict__ k,
                                                   const float* __restrict__ v,
                                                   float* __restrict__ o) {
    __shared__ __align__(16) unsigned char smem[27840];
    f16x8*          Kh2 = (f16x8*)smem;                 // [0,16384): 1024 keys {hi4|lo4}
    unsigned short* VTu = (unsigned short*)(smem + 16384); // 5 rows x 1040 f16 (permuted)
    float*          lsc = (float*)(smem + 26784);       // [26784,27808): l exchange
    int bh = blockIdx.x >> 2;
    int row0 = (blockIdx.x & 3) * 256;
    int tid = threadIdx.x;
    const float4* kp4 = (const float4*)(k + bh * 4096);
    const float4* vp4 = (const float4*)(v + bh * 4096);
    #pragma unroll
    for (int i = 0; i < 4; i++) {                       // stage K (Markidis) + V^T (f16)
        int key = i * 256 + tid;
        float4 kf = kp4[key];
        f16x8 kk;
        kk[0] = (_Float16)kf.x; kk[4] = (_Float16)(kf.x - (float)kk[0]);
        kk[1] = (_Float16)kf.y; kk[5] = (_Float16)(kf.y - (float)kk[1]);
        kk[2] = (_Float16)kf.z; kk[6] = (_Float16)(kf.z - (float)kk[2]);
        kk[3] = (_Float16)kf.w; kk[7] = (_Float16)(kf.w - (float)kk[3]);
        Kh2[key] = kk;
        float4 vf = vp4[key];
        int pos = (key & ~31) | (((key & 15) >> 2) << 3)
                | (((key >> 4) & 1) << 2) | (key & 3);  // kappa-permutation (bijective)
        VTu[0 * 1040 + pos] = __builtin_bit_cast(unsigned short, (_Float16)vf.x);
        VTu[1 * 1040 + pos] = __builtin_bit_cast(unsigned short, (_Float16)vf.y);
        VTu[2 * 1040 + pos] = __builtin_bit_cast(unsigned short, (_Float16)vf.z);
        VTu[3 * 1040 + pos] = __builtin_bit_cast(unsigned short, (_Float16)vf.w);
        VTu[4 * 1040 + key] = 0x3C00;                   // ones row (position-free)
    }
    int w = tid >> 6, lane = tid & 63;
    int c = lane & 15, quad = lane >> 4;
    int mv = (c < 5) ? c : 4;                           // clamp -> broadcast ones-row
    const float C1 = 0.5f * 1.44269504088896f;          // scale*log2(e), folded into Q
    const float4* qp4 = (const float4*)(q + bh * 4096);
    f16x8 bq[4];
    #pragma unroll
    for (int s = 0; s < 4; s++) {                       // Q Markidis B-frags (4 strips)
        int rowg = row0 + w * 64 + s * 16 + c;
        float4 qv = qp4[rowg];
        float qx = qv.x * C1, qy = qv.y * C1, qz = qv.z * C1, qw = qv.w * C1;
        _Float16 hx = (_Float16)qx, hy = (_Float16)qy,
                 hz = (_Float16)qz, hw = (_Float16)qw;
        _Float16 gx = (_Float16)(qx - (float)hx), gy = (_Float16)(qy - (float)hy),
                 gz = (_Float16)(qz - (float)hz), gw = (_Float16)(qw - (float)hw);
        f16x8 a = {};
        if (quad == 0) {
            a[0] = hx; a[1] = hy; a[2] = hz; a[3] = hw;
            a[4] = hx; a[5] = hy; a[6] = hz; a[7] = hw;
        } else if (quad == 1) {
            a[0] = gx; a[1] = gy; a[2] = gz; a[3] = gw;
            a[4] = gx; a[5] = gy; a[6] = gz; a[7] = gw;
        }
        bq[s] = a;
    }
    __syncthreads();
    f32x4 acc[4];
    #pragma unroll
    for (int s = 0; s < 4; s++) acc[s] = (f32x4)(0.f);
    #pragma unroll 2
    for (int T = 0; T < 32; T++) {                      // 32-key tile-pairs
        f16x8 ka0 = Kh2[(2 * T) * 16 + c];              // ds_read_b128 (2-way: free)
        f16x8 ka1 = Kh2[(2 * T + 1) * 16 + c];
        const uint4* vptr = (const uint4*)((const unsigned char*)VTu
                                           + mv * 2080 + T * 64 + quad * 16);
        f16x8 va = __builtin_bit_cast(f16x8, *vptr);    // V^T A-frag: 32 keys, 1 read
        #pragma unroll
        for (int s = 0; s < 4; s++) {
            f32x4 S0 = __builtin_amdgcn_mfma_f32_16x16x32_f16(ka0, bq[s],
                                                              (f32x4)(0.f), 0, 0, 0);
            f32x4 S1 = __builtin_amdgcn_mfma_f32_16x16x32_f16(ka1, bq[s],
                                                              (f32x4)(0.f), 0, 0, 0);
            f16x8 pb;
            pb[0] = (_Float16)__builtin_amdgcn_exp2f(S0[0] - 14.f);  // RTN cvt
            pb[1] = (_Float16)__builtin_amdgcn_exp2f(S0[1] - 14.f);
            pb[2] = (_Float16)__builtin_amdgcn_exp2f(S0[2] - 14.f);
            pb[3] = (_Float16)__builtin_amdgcn_exp2f(S0[3] - 14.f);
            pb[4] = (_Float16)__builtin_amdgcn_exp2f(S1[0] - 14.f);
            pb[5] = (_Float16)__builtin_amdgcn_exp2f(S1[1] - 14.f);
            pb[6] = (_Float16)__builtin_amdgcn_exp2f(S1[2] - 14.f);
            pb[7] = (_Float16)__builtin_amdgcn_exp2f(S1[3] - 14.f);
            acc[s] = __builtin_amdgcn_mfma_f32_16x16x32_f16(va, pb, acc[s], 0, 0, 0);
        }
    }
    // Epilogue: quad1 reg0 holds l (row 4 = ones-row); quad0 regs 0-3 hold O dims.
    if (quad == 1) {
        #pragma unroll
        for (int s = 0; s < 4; s++) lsc[w * 64 + s * 16 + c] = acc[s][0];
    }
    __syncthreads();
    if (quad == 0) {
        int b0 = bh >> 4, h = bh & 15;
        #pragma unroll
        for (int s = 0; s < 4; s++) {
            float rl = 1.f / lsc[w * 64 + s * 16 + c];
            int rowg = row0 + w * 64 + s * 16 + c;
            float4 res = { acc[s][0] * rl, acc[s][1] * rl,
                           acc[s][2] * rl, acc[s][3] * rl };
            *(float4*)&o[(b0 * 1024 + rowg) * 64 + h * 4] = res;
        }
    }
}

// ---------------- Kernel D: o @ w_proj + BN + max-unpool scatter ----------------
__global__ __launch_bounds__(256) void proj_kernel(const float* __restrict__ o,
                                                   const float* __restrict__ w_proj,
                                                   const float* __restrict__ gamma,
                                                   const float* __restrict__ beta,
                                                   const float* __restrict__ mean,
                                                   const float* __restrict__ var,
                                                   const int* __restrict__ idx,
                                                   float* __restrict__ out) {
    __shared__ float ws[64 * 64];                       // w_proj
    int b = blockIdx.x >> 5, hp = blockIdx.x & 31;
    int tid = threadIdx.x;
    for (int i = tid; i < 4096; i += 256) ws[i] = w_proj[i];
    int wp = tid & 31, cg = tid >> 5;                   // 8 c-groups x 32 wp
    float oreg[64];                                     // my o row in registers
    const float* orow = o + (b * 1024 + hp * 32 + wp) * 64;
    #pragma unroll
    for (int a4 = 0; a4 < 16; a4++) {
        float4 t4 = ((const float4*)orow)[a4];
        oreg[a4 * 4] = t4.x; oreg[a4 * 4 + 1] = t4.y;
        oreg[a4 * 4 + 2] = t4.z; oreg[a4 * 4 + 3] = t4.w;
    }
    __syncthreads();
    #pragma unroll
    for (int g = 0; g < 2; g++) {
        int c0 = cg * 8 + g * 4;                        // 4 consecutive channels
        float4 acc = {0.f, 0.f, 0.f, 0.f};
        #pragma unroll
        for (int a = 0; a < 64; a++) {
            float4 wv = *(const float4*)&ws[a * 64 + c0];   // b128, 2-addr broadcast
            acc.x += oreg[a] * wv.x; acc.y += oreg[a] * wv.y;
            acc.z += oreg[a] * wv.z; acc.w += oreg[a] * wv.w;
        }
        float accs[4] = { acc.x, acc.y, acc.z, acc.w };
        #pragma unroll
        for (int i = 0; i < 4; i++) {
            int c = c0 + i;
            float inv = gamma[c] * rsqrtf(var[c] + 1e-5f);
            float val = accs[i] * inv + (beta[c] - mean[c] * inv);
            int id = idx[((b * 64 + c) * 32 + hp) * 32 + wp];
            int base = ((b * 64 + c) * 64 + 2 * hp) * 64 + 2 * wp;
            float2 r0 = { id == 0 ? val : 0.f, id == 1 ? val : 0.f };
            float2 r1 = { id == 2 ? val : 0.f, id == 3 ? val : 0.f };
            *(float2*)&out[base] = r0;                  // row 2hp,   cols 2wp..2wp+1
            *(float2*)&out[base + 64] = r1;             // row 2hp+1
        }
    }
}

extern "C" void kernel_launch(void* const* d_in, const int* in_sizes, int n_in,
                              void* d_out, int out_size, void* d_ws, size_t ws_size,
                              hipStream_t stream) {
    const float* x      = (const float*)d_in[0];
    const float* w_qkv  = (const float*)d_in[1];
    const float* w_proj = (const float*)d_in[2];
    const float* gamma  = (const float*)d_in[3];
    const float* beta   = (const float*)d_in[4];
    const float* bn_mean= (const float*)d_in[5];
    const float* bn_var = (const float*)d_in[6];
    float* out = (float*)d_out;

    const int SEG = 524288;                             // 8*1024*64
    float* ws = (float*)d_ws;
    float* t   = ws;
    int*   idx = (int*)(ws + SEG);
    float* q   = ws + 2 * SEG;
    float* k   = ws + 3 * SEG;
    float* v   = ws + 4 * SEG;
    float* o   = ws + 5 * SEG;

    pool_kernel<<<2048, 256, 0, stream>>>(x, t, idx);
    qkv_kernel<<<512, 192, 0, stream>>>(t, w_qkv, q, k, v);
    attn_kernel<<<512, 256, 0, stream>>>(q, k, v, o);
    proj_kernel<<<256, 256, 0, stream>>>(o, w_proj, gamma, beta, bn_mean, bn_var, idx, out);
}

// Round 17
// 120.926 us; speedup vs baseline: 1.1202x; 1.0230x over previous
//
#include <hip/hip_runtime.h>
#include <hip/hip_bf16.h>

// Problem: B=8, C=DIM=64, H=W=64 -> pooled 32x32 (N=1024 tokens), 16 heads x d=4.
// ws layout (floats): t[524288] | idx[524288 ints] | q[524288] | k[524288] | v[524288]
//                     | o[524288] (normalized attention output, (B,N,64))
// q/k/v layout: (B, H=16, N=1024, D=4) contiguous -> per (b,h) a 4096-float slab.

typedef float    f32x4 __attribute__((ext_vector_type(4)));
typedef _Float16 f16x8 __attribute__((ext_vector_type(8)));
typedef unsigned int uint32_tt;

// ---------------- Kernel A: 2x2 maxpool + argmax ----------------
__global__ __launch_bounds__(256) void pool_kernel(const float* __restrict__ x,
                                                   float* __restrict__ t,
                                                   int* __restrict__ idx) {
    int g = blockIdx.x * 256 + threadIdx.x;            // covers 8*64*32*32 = 524288
    int wp = g & 31, hp = (g >> 5) & 31, c = (g >> 10) & 63, b = g >> 16;
    const float* px = x + (((b * 64 + c) * 64 + 2 * hp) * 64 + 2 * wp);
    float2 r0 = *(const float2*)px;
    float2 r1 = *(const float2*)(px + 64);
    float best = r0.x; int bi = 0;                      // first-max semantics (strict >)
    if (r0.y > best) { best = r0.y; bi = 1; }
    if (r1.x > best) { best = r1.x; bi = 2; }
    if (r1.y > best) { best = r1.y; bi = 3; }
    int n = hp * 32 + wp;
    t[(b * 1024 + n) * 64 + c] = best;
    idx[g] = bi;                                        // layout (b,c,hp,wp)
}

// ---------------- Kernel B: qkv = t @ w_qkv, scatter to (B,H,N,4) ----------------
__global__ __launch_bounds__(192) void qkv_kernel(const float* __restrict__ t,
                                                  const float* __restrict__ w_qkv,
                                                  float* __restrict__ q,
                                                  float* __restrict__ k,
                                                  float* __restrict__ v) {
    __shared__ float trow[16 * 64];                     // 16 token rows
    int tid = threadIdx.x;                              // 0..191
    int row0 = blockIdx.x * 16;
    for (int i = tid; i < 1024; i += 192) trow[i] = t[row0 * 64 + i];
    int j  = tid % 96;                                  // my column pair {j, j+96}
    int rh = tid / 96;                                  // my row half (8 rows)
    float wc0[64], wc1[64];
    #pragma unroll
    for (int c = 0; c < 64; c++) {
        wc0[c] = w_qkv[c * 192 + j];
        wc1[c] = w_qkv[c * 192 + j + 96];
    }
    __syncthreads();
    int s0 = j >> 6, h0 = (j >> 2) & 15, d0 = j & 3;
    int j1 = j + 96;
    int s1 = j1 >> 6, h1 = (j1 >> 2) & 15, d1 = j1 & 3;
    float* dst0 = (s0 == 0) ? q : (s0 == 1) ? k : v;
    float* dst1 = (s1 == 0) ? q : (s1 == 1) ? k : v;
    for (int r = 0; r < 8; r++) {
        int row = rh * 8 + r;
        const float4* tr = (const float4*)&trow[row * 64];
        float a0 = 0.f, a1 = 0.f;
        #pragma unroll
        for (int c4 = 0; c4 < 16; c4++) {
            float4 tv = tr[c4];                         // <=2-way LDS broadcast: free
            a0 += tv.x * wc0[c4 * 4] + tv.y * wc0[c4 * 4 + 1]
                + tv.z * wc0[c4 * 4 + 2] + tv.w * wc0[c4 * 4 + 3];
            a1 += tv.x * wc1[c4 * 4] + tv.y * wc1[c4 * 4 + 1]
                + tv.z * wc1[c4 * 4 + 2] + tv.w * wc1[c4 * 4 + 3];
        }
        int ng = row0 + row, b = ng >> 10, n = ng & 1023;
        dst0[((b * 16 + h0) * 1024 + n) * 4 + d0] = a0;
        dst1[((b * 16 + h1) * 1024 + n) * 4 + d1] = a1;
    }
}

// ---------------- Kernel C: dual-MFMA attention, 32-key tile-pairs ------------------
// R16 post-mortem: 123.7 total; loop is stall-amplified (gains land ~2x the pure
// issue-cycle arithmetic). Two VALU shavings, structure otherwise frozen:
//  (1) the -14 exponent shift now rides in MFMA1's C operand (D = K*Q + C with
//      C = {-14}) -- removes 32 v_sub_f32 per tile-pair at zero accuracy cost;
//  (2) P packs via v_cvt_pkrtz (2 converts/instr, RTZ) -- 32 cvt -> 16 pkrtz.
// Scheme recap (R15/R16-proven):
//  MFMA1: S^T-14 = K x Q^T + C.  A = {kh0..3|kl0..3} (lane m=key); B = Q Markidis
//         (quad0={qh|qh}, quad1={ql|ql}) -> fp32-exact S. C row = quad*4+reg (m89).
//  MFMA2: O^T = V^T x P^T over 32 keys/instr: V plain f16 in kappa-permuted layout
//         (slot j of quad q <-> key 32T + (j<4 ? q*4+j : 16+q*4+j-4)); ones-row m=4
//         emits l = sum(p); exp2(S-14) shift cancels in O/l (f16-range safe).
// grid = 128 bh * 4 row-blocks of 256; block = 4 waves, wave = 4 strips of 16 rows.
__global__ __launch_bounds__(256) void attn_kernel(const float* __restrict__ q,
                                                   const float* __restrict__ k,
                                                   const float* __restrict__ v,
                                                   float* __restrict__ o) {
    __shared__ __align__(16) unsigned char smem[27840];
    f16x8*          Kh2 = (f16x8*)smem;                 // [0,16384): 1024 keys {hi4|lo4}
    unsigned short* VTu = (unsigned short*)(smem + 16384); // 5 rows x 1040 f16 (permuted)
    float*          lsc = (float*)(smem + 26784);       // [26784,27808): l exchange
    int bh = blockIdx.x >> 2;
    int row0 = (blockIdx.x & 3) * 256;
    int tid = threadIdx.x;
    const float4* kp4 = (const float4*)(k + bh * 4096);
    const float4* vp4 = (const float4*)(v + bh * 4096);
    #pragma unroll
    for (int i = 0; i < 4; i++) {                       // stage K (Markidis) + V^T (f16)
        int key = i * 256 + tid;
        float4 kf = kp4[key];
        f16x8 kk;
        kk[0] = (_Float16)kf.x; kk[4] = (_Float16)(kf.x - (float)kk[0]);
        kk[1] = (_Float16)kf.y; kk[5] = (_Float16)(kf.y - (float)kk[1]);
        kk[2] = (_Float16)kf.z; kk[6] = (_Float16)(kf.z - (float)kk[2]);
        kk[3] = (_Float16)kf.w; kk[7] = (_Float16)(kf.w - (float)kk[3]);
        Kh2[key] = kk;
        float4 vf = vp4[key];
        int pos = (key & ~31) | (((key & 15) >> 2) << 3)
                | (((key >> 4) & 1) << 2) | (key & 3);  // kappa-permutation (bijective)
        VTu[0 * 1040 + pos] = __builtin_bit_cast(unsigned short, (_Float16)vf.x);
        VTu[1 * 1040 + pos] = __builtin_bit_cast(unsigned short, (_Float16)vf.y);
        VTu[2 * 1040 + pos] = __builtin_bit_cast(unsigned short, (_Float16)vf.z);
        VTu[3 * 1040 + pos] = __builtin_bit_cast(unsigned short, (_Float16)vf.w);
        VTu[4 * 1040 + key] = 0x3C00;                   // ones row (position-free)
    }
    int w = tid >> 6, lane = tid & 63;
    int c = lane & 15, quad = lane >> 4;
    int mv = (c < 5) ? c : 4;                           // clamp -> broadcast ones-row
    const float C1 = 0.5f * 1.44269504088896f;          // scale*log2(e), folded into Q
    const float4* qp4 = (const float4*)(q + bh * 4096);
    f16x8 bq[4];
    #pragma unroll
    for (int s = 0; s < 4; s++) {                       // Q Markidis B-frags (4 strips)
        int rowg = row0 + w * 64 + s * 16 + c;
        float4 qv = qp4[rowg];
        float qx = qv.x * C1, qy = qv.y * C1, qz = qv.z * C1, qw = qv.w * C1;
        _Float16 hx = (_Float16)qx, hy = (_Float16)qy,
                 hz = (_Float16)qz, hw = (_Float16)qw;
        _Float16 gx = (_Float16)(qx - (float)hx), gy = (_Float16)(qy - (float)hy),
                 gz = (_Float16)(qz - (float)hz), gw = (_Float16)(qw - (float)hw);
        f16x8 a = {};
        if (quad == 0) {
            a[0] = hx; a[1] = hy; a[2] = hz; a[3] = hw;
            a[4] = hx; a[5] = hy; a[6] = hz; a[7] = hw;
        } else if (quad == 1) {
            a[0] = gx; a[1] = gy; a[2] = gz; a[3] = gw;
            a[4] = gx; a[5] = gy; a[6] = gz; a[7] = gw;
        }
        bq[s] = a;
    }
    __syncthreads();
    f32x4 acc[4];
    #pragma unroll
    for (int s = 0; s < 4; s++) acc[s] = (f32x4)(0.f);
    const f32x4 cm14 = { -14.f, -14.f, -14.f, -14.f }; // shift rides in MFMA1's C
    #pragma unroll 2
    for (int T = 0; T < 32; T++) {                      // 32-key tile-pairs
        f16x8 ka0 = Kh2[(2 * T) * 16 + c];              // ds_read_b128 (broadcast)
        f16x8 ka1 = Kh2[(2 * T + 1) * 16 + c];
        const uint4* vptr = (const uint4*)((const unsigned char*)VTu
                                           + mv * 2080 + T * 64 + quad * 16);
        f16x8 va = __builtin_bit_cast(f16x8, *vptr);    // V^T A-frag: 32 keys, 1 read
        #pragma unroll
        for (int s = 0; s < 4; s++) {
            f32x4 S0 = __builtin_amdgcn_mfma_f32_16x16x32_f16(ka0, bq[s], cm14, 0, 0, 0);
            f32x4 S1 = __builtin_amdgcn_mfma_f32_16x16x32_f16(ka1, bq[s], cm14, 0, 0, 0);
            float p00 = __builtin_amdgcn_exp2f(S0[0]);  // bare v_exp_f32 (trans pipe)
            float p01 = __builtin_amdgcn_exp2f(S0[1]);
            float p02 = __builtin_amdgcn_exp2f(S0[2]);
            float p03 = __builtin_amdgcn_exp2f(S0[3]);
            float p10 = __builtin_amdgcn_exp2f(S1[0]);
            float p11 = __builtin_amdgcn_exp2f(S1[1]);
            float p12 = __builtin_amdgcn_exp2f(S1[2]);
            float p13 = __builtin_amdgcn_exp2f(S1[3]);
            uint4 pbu;                                  // v_cvt_pkrtz: 2 converts/instr
            pbu.x = __builtin_bit_cast(uint32_tt, __builtin_amdgcn_cvt_pkrtz(p00, p01));
            pbu.y = __builtin_bit_cast(uint32_tt, __builtin_amdgcn_cvt_pkrtz(p02, p03));
            pbu.z = __builtin_bit_cast(uint32_tt, __builtin_amdgcn_cvt_pkrtz(p10, p11));
            pbu.w = __builtin_bit_cast(uint32_tt, __builtin_amdgcn_cvt_pkrtz(p12, p13));
            f16x8 pb = __builtin_bit_cast(f16x8, pbu);
            acc[s] = __builtin_amdgcn_mfma_f32_16x16x32_f16(va, pb, acc[s], 0, 0, 0);
        }
    }
    // Epilogue: quad1 reg0 holds l (row 4 = ones-row); quad0 regs 0-3 hold O dims.
    if (quad == 1) {
        #pragma unroll
        for (int s = 0; s < 4; s++) lsc[w * 64 + s * 16 + c] = acc[s][0];
    }
    __syncthreads();
    if (quad == 0) {
        int b0 = bh >> 4, h = bh & 15;
        #pragma unroll
        for (int s = 0; s < 4; s++) {
            float rl = 1.f / lsc[w * 64 + s * 16 + c];
            int rowg = row0 + w * 64 + s * 16 + c;
            float4 res = { acc[s][0] * rl, acc[s][1] * rl,
                           acc[s][2] * rl, acc[s][3] * rl };
            *(float4*)&o[(b0 * 1024 + rowg) * 64 + h * 4] = res;
        }
    }
}

// ---------------- Kernel D: o @ w_proj + BN + max-unpool scatter ----------------
__global__ __launch_bounds__(256) void proj_kernel(const float* __restrict__ o,
                                                   const float* __restrict__ w_proj,
                                                   const float* __restrict__ gamma,
                                                   const float* __restrict__ beta,
                                                   const float* __restrict__ mean,
                                                   const float* __restrict__ var,
                                                   const int* __restrict__ idx,
                                                   float* __restrict__ out) {
    __shared__ float ws[64 * 64];                       // w_proj
    int b = blockIdx.x >> 5, hp = blockIdx.x & 31;
    int tid = threadIdx.x;
    for (int i = tid; i < 4096; i += 256) ws[i] = w_proj[i];
    int wp = tid & 31, cg = tid >> 5;                   // 8 c-groups x 32 wp
    float oreg[64];                                     // my o row in registers
    const float* orow = o + (b * 1024 + hp * 32 + wp) * 64;
    #pragma unroll
    for (int a4 = 0; a4 < 16; a4++) {
        float4 t4 = ((const float4*)orow)[a4];
        oreg[a4 * 4] = t4.x; oreg[a4 * 4 + 1] = t4.y;
        oreg[a4 * 4 + 2] = t4.z; oreg[a4 * 4 + 3] = t4.w;
    }
    __syncthreads();
    #pragma unroll
    for (int g = 0; g < 2; g++) {
        int c0 = cg * 8 + g * 4;                        // 4 consecutive channels
        float4 acc = {0.f, 0.f, 0.f, 0.f};
        #pragma unroll
        for (int a = 0; a < 64; a++) {
            float4 wv = *(const float4*)&ws[a * 64 + c0];   // b128, 2-addr broadcast
            acc.x += oreg[a] * wv.x; acc.y += oreg[a] * wv.y;
            acc.z += oreg[a] * wv.z; acc.w += oreg[a] * wv.w;
        }
        float accs[4] = { acc.x, acc.y, acc.z, acc.w };
        #pragma unroll
        for (int i = 0; i < 4; i++) {
            int c = c0 + i;
            float inv = gamma[c] * rsqrtf(var[c] + 1e-5f);
            float val = accs[i] * inv + (beta[c] - mean[c] * inv);
            int id = idx[((b * 64 + c) * 32 + hp) * 32 + wp];
            int base = ((b * 64 + c) * 64 + 2 * hp) * 64 + 2 * wp;
            float2 r0 = { id == 0 ? val : 0.f, id == 1 ? val : 0.f };
            float2 r1 = { id == 2 ? val : 0.f, id == 3 ? val : 0.f };
            *(float2*)&out[base] = r0;                  // row 2hp,   cols 2wp..2wp+1
            *(float2*)&out[base + 64] = r1;             // row 2hp+1
        }
    }
}

extern "C" void kernel_launch(void* const* d_in, const int* in_sizes, int n_in,
                              void* d_out, int out_size, void* d_ws, size_t ws_size,
                              hipStream_t stream) {
    const float* x      = (const float*)d_in[0];
    const float* w_qkv  = (const float*)d_in[1];
    const float* w_proj = (const float*)d_in[2];
    const float* gamma  = (const float*)d_in[3];
    const float* beta   = (const float*)d_in[4];
    const float* bn_mean= (const float*)d_in[5];
    const float* bn_var = (const float*)d_in[6];
    float* out = (float*)d_out;

    const int SEG = 524288;                             // 8*1024*64
    float* ws = (float*)d_ws;
    float* t   = ws;
    int*   idx = (int*)(ws + SEG);
    float* q   = ws + 2 * SEG;
    float* k   = ws + 3 * SEG;
    float* v   = ws + 4 * SEG;
    float* o   = ws + 5 * SEG;

    pool_kernel<<<2048, 256, 0, stream>>>(x, t, idx);
    qkv_kernel<<<512, 192, 0, stream>>>(t, w_qkv, q, k, v);
    attn_kernel<<<512, 256, 0, stream>>>(q, k, v, o);
    proj_kernel<<<256, 256, 0, stream>>>(o, w_proj, gamma, beta, bn_mean, bn_var, idx, out);
}

// Round 18
// 119.075 us; speedup vs baseline: 1.1376x; 1.0155x over previous
//
#include <hip/hip_runtime.h>
#include <hip/hip_bf16.h>

// Problem: B=8, C=DIM=64, H=W=64 -> pooled 32x32 (N=1024 tokens), 16 heads x d=4.
// ws layout (floats): t[524288] | idx[524288 ints] | q[524288] | k[524288] | v[524288]
//                     | o[524288] (normalized attention output, (B,N,64))
// q/k/v layout: (B, H=16, N=1024, D=4) contiguous -> per (b,h) a 4096-float slab.

typedef float    f32x4 __attribute__((ext_vector_type(4)));
typedef _Float16 f16x8 __attribute__((ext_vector_type(8)));
typedef unsigned int uint32_tt;

// ---------------- Kernel A: 2x2 maxpool + argmax ----------------
__global__ __launch_bounds__(256) void pool_kernel(const float* __restrict__ x,
                                                   float* __restrict__ t,
                                                   int* __restrict__ idx) {
    int g = blockIdx.x * 256 + threadIdx.x;            // covers 8*64*32*32 = 524288
    int wp = g & 31, hp = (g >> 5) & 31, c = (g >> 10) & 63, b = g >> 16;
    const float* px = x + (((b * 64 + c) * 64 + 2 * hp) * 64 + 2 * wp);
    float2 r0 = *(const float2*)px;
    float2 r1 = *(const float2*)(px + 64);
    float best = r0.x; int bi = 0;                      // first-max semantics (strict >)
    if (r0.y > best) { best = r0.y; bi = 1; }
    if (r1.x > best) { best = r1.x; bi = 2; }
    if (r1.y > best) { best = r1.y; bi = 3; }
    int n = hp * 32 + wp;
    t[(b * 1024 + n) * 64 + c] = best;
    idx[g] = bi;                                        // layout (b,c,hp,wp)
}

// ---------------- Kernel B: qkv = t @ w_qkv, scatter to (B,H,N,4) ----------------
__global__ __launch_bounds__(192) void qkv_kernel(const float* __restrict__ t,
                                                  const float* __restrict__ w_qkv,
                                                  float* __restrict__ q,
                                                  float* __restrict__ k,
                                                  float* __restrict__ v) {
    __shared__ float trow[16 * 64];                     // 16 token rows
    int tid = threadIdx.x;                              // 0..191
    int row0 = blockIdx.x * 16;
    for (int i = tid; i < 1024; i += 192) trow[i] = t[row0 * 64 + i];
    int j  = tid % 96;                                  // my column pair {j, j+96}
    int rh = tid / 96;                                  // my row half (8 rows)
    float wc0[64], wc1[64];
    #pragma unroll
    for (int c = 0; c < 64; c++) {
        wc0[c] = w_qkv[c * 192 + j];
        wc1[c] = w_qkv[c * 192 + j + 96];
    }
    __syncthreads();
    int s0 = j >> 6, h0 = (j >> 2) & 15, d0 = j & 3;
    int j1 = j + 96;
    int s1 = j1 >> 6, h1 = (j1 >> 2) & 15, d1 = j1 & 3;
    float* dst0 = (s0 == 0) ? q : (s0 == 1) ? k : v;
    float* dst1 = (s1 == 0) ? q : (s1 == 1) ? k : v;
    for (int r = 0; r < 8; r++) {
        int row = rh * 8 + r;
        const float4* tr = (const float4*)&trow[row * 64];
        float a0 = 0.f, a1 = 0.f;
        #pragma unroll
        for (int c4 = 0; c4 < 16; c4++) {
            float4 tv = tr[c4];                         // <=2-way LDS broadcast: free
            a0 += tv.x * wc0[c4 * 4] + tv.y * wc0[c4 * 4 + 1]
                + tv.z * wc0[c4 * 4 + 2] + tv.w * wc0[c4 * 4 + 3];
            a1 += tv.x * wc1[c4 * 4] + tv.y * wc1[c4 * 4 + 1]
                + tv.z * wc1[c4 * 4 + 2] + tv.w * wc1[c4 * 4 + 3];
        }
        int ng = row0 + row, b = ng >> 10, n = ng & 1023;
        dst0[((b * 16 + h0) * 1024 + n) * 4 + d0] = a0;
        dst1[((b * 16 + h1) * 1024 + n) * 4 + d1] = a1;
    }
}

// ---------------- Kernel C: dual-MFMA attention, 32-key tile-pairs ------------------
// R17 post-mortem: attn ~22us vs 6.8us trans floor -- dependency-chain stalls at
// 2 waves/SIMD (loop is no longer issue-bound after R15-R17 thinning). This round:
// grid 512 -> 1024 (8 row-blocks of 128; wave = 2 strips), doubling waves/SIMD to 4
// at halved per-wave registers (acc 16->8, bq 16->8). Loop body, MFMA scheme,
// epilogue all frozen from R17:
//  MFMA1: S^T-14 = K x Q^T + C(-14).  A = {kh|kl} Markidis (lane m=key); B = Q
//         Markidis (quad0={qh|qh}, quad1={ql|ql}) -> fp32-exact S. C row=quad*4+reg.
//  MFMA2: O^T = V^T x P^T over 32 keys/instr: V plain f16, kappa-permuted layout
//         (slot j of quad q <-> key 32T + (j<4 ? q*4+j : 16+q*4+j-4)); ones-row m=4
//         emits l = sum(p); exp2(S-14) cancels in O/l; P packs via v_cvt_pkrtz.
// grid = 128 bh * 8 row-blocks of 128; block = 4 waves, wave = 2 strips of 16 rows.
__global__ __launch_bounds__(256) void attn_kernel(const float* __restrict__ q,
                                                   const float* __restrict__ k,
                                                   const float* __restrict__ v,
                                                   float* __restrict__ o) {
    __shared__ __align__(16) unsigned char smem[27840];
    f16x8*          Kh2 = (f16x8*)smem;                 // [0,16384): 1024 keys {hi4|lo4}
    unsigned short* VTu = (unsigned short*)(smem + 16384); // 5 rows x 1040 f16 (permuted)
    float*          lsc = (float*)(smem + 26784);       // l exchange
    int bh = blockIdx.x >> 3;
    int row0 = (blockIdx.x & 7) * 128;
    int tid = threadIdx.x;
    const float4* kp4 = (const float4*)(k + bh * 4096);
    const float4* vp4 = (const float4*)(v + bh * 4096);
    #pragma unroll
    for (int i = 0; i < 4; i++) {                       // stage K (Markidis) + V^T (f16)
        int key = i * 256 + tid;
        float4 kf = kp4[key];
        f16x8 kk;
        kk[0] = (_Float16)kf.x; kk[4] = (_Float16)(kf.x - (float)kk[0]);
        kk[1] = (_Float16)kf.y; kk[5] = (_Float16)(kf.y - (float)kk[1]);
        kk[2] = (_Float16)kf.z; kk[6] = (_Float16)(kf.z - (float)kk[2]);
        kk[3] = (_Float16)kf.w; kk[7] = (_Float16)(kf.w - (float)kk[3]);
        Kh2[key] = kk;
        float4 vf = vp4[key];
        int pos = (key & ~31) | (((key & 15) >> 2) << 3)
                | (((key >> 4) & 1) << 2) | (key & 3);  // kappa-permutation (bijective)
        VTu[0 * 1040 + pos] = __builtin_bit_cast(unsigned short, (_Float16)vf.x);
        VTu[1 * 1040 + pos] = __builtin_bit_cast(unsigned short, (_Float16)vf.y);
        VTu[2 * 1040 + pos] = __builtin_bit_cast(unsigned short, (_Float16)vf.z);
        VTu[3 * 1040 + pos] = __builtin_bit_cast(unsigned short, (_Float16)vf.w);
        VTu[4 * 1040 + key] = 0x3C00;                   // ones row (position-free)
    }
    int w = tid >> 6, lane = tid & 63;
    int c = lane & 15, quad = lane >> 4;
    int mv = (c < 5) ? c : 4;                           // clamp -> broadcast ones-row
    const float C1 = 0.5f * 1.44269504088896f;          // scale*log2(e), folded into Q
    const float4* qp4 = (const float4*)(q + bh * 4096);
    f16x8 bq[2];
    #pragma unroll
    for (int s = 0; s < 2; s++) {                       // Q Markidis B-frags (2 strips)
        int rowg = row0 + w * 32 + s * 16 + c;
        float4 qv = qp4[rowg];
        float qx = qv.x * C1, qy = qv.y * C1, qz = qv.z * C1, qw = qv.w * C1;
        _Float16 hx = (_Float16)qx, hy = (_Float16)qy,
                 hz = (_Float16)qz, hw = (_Float16)qw;
        _Float16 gx = (_Float16)(qx - (float)hx), gy = (_Float16)(qy - (float)hy),
                 gz = (_Float16)(qz - (float)hz), gw = (_Float16)(qw - (float)hw);
        f16x8 a = {};
        if (quad == 0) {
            a[0] = hx; a[1] = hy; a[2] = hz; a[3] = hw;
            a[4] = hx; a[5] = hy; a[6] = hz; a[7] = hw;
        } else if (quad == 1) {
            a[0] = gx; a[1] = gy; a[2] = gz; a[3] = gw;
            a[4] = gx; a[5] = gy; a[6] = gz; a[7] = gw;
        }
        bq[s] = a;
    }
    __syncthreads();
    f32x4 acc[2];
    acc[0] = (f32x4)(0.f); acc[1] = (f32x4)(0.f);
    const f32x4 cm14 = { -14.f, -14.f, -14.f, -14.f }; // shift rides in MFMA1's C
    #pragma unroll 2
    for (int T = 0; T < 32; T++) {                      // 32-key tile-pairs
        f16x8 ka0 = Kh2[(2 * T) * 16 + c];              // ds_read_b128 (broadcast)
        f16x8 ka1 = Kh2[(2 * T + 1) * 16 + c];
        const uint4* vptr = (const uint4*)((const unsigned char*)VTu
                                           + mv * 2080 + T * 64 + quad * 16);
        f16x8 va = __builtin_bit_cast(f16x8, *vptr);    // V^T A-frag: 32 keys, 1 read
        #pragma unroll
        for (int s = 0; s < 2; s++) {
            f32x4 S0 = __builtin_amdgcn_mfma_f32_16x16x32_f16(ka0, bq[s], cm14, 0, 0, 0);
            f32x4 S1 = __builtin_amdgcn_mfma_f32_16x16x32_f16(ka1, bq[s], cm14, 0, 0, 0);
            float p00 = __builtin_amdgcn_exp2f(S0[0]);  // bare v_exp_f32 (trans pipe)
            float p01 = __builtin_amdgcn_exp2f(S0[1]);
            float p02 = __builtin_amdgcn_exp2f(S0[2]);
            float p03 = __builtin_amdgcn_exp2f(S0[3]);
            float p10 = __builtin_amdgcn_exp2f(S1[0]);
            float p11 = __builtin_amdgcn_exp2f(S1[1]);
            float p12 = __builtin_amdgcn_exp2f(S1[2]);
            float p13 = __builtin_amdgcn_exp2f(S1[3]);
            uint4 pbu;                                  // v_cvt_pkrtz: 2 converts/instr
            pbu.x = __builtin_bit_cast(uint32_tt, __builtin_amdgcn_cvt_pkrtz(p00, p01));
            pbu.y = __builtin_bit_cast(uint32_tt, __builtin_amdgcn_cvt_pkrtz(p02, p03));
            pbu.z = __builtin_bit_cast(uint32_tt, __builtin_amdgcn_cvt_pkrtz(p10, p11));
            pbu.w = __builtin_bit_cast(uint32_tt, __builtin_amdgcn_cvt_pkrtz(p12, p13));
            f16x8 pb = __builtin_bit_cast(f16x8, pbu);
            acc[s] = __builtin_amdgcn_mfma_f32_16x16x32_f16(va, pb, acc[s], 0, 0, 0);
        }
    }
    // Epilogue: quad1 reg0 holds l (row 4 = ones-row); quad0 regs 0-3 hold O dims.
    if (quad == 1) {
        #pragma unroll
        for (int s = 0; s < 2; s++) lsc[w * 32 + s * 16 + c] = acc[s][0];
    }
    __syncthreads();
    if (quad == 0) {
        int b0 = bh >> 4, h = bh & 15;
        #pragma unroll
        for (int s = 0; s < 2; s++) {
            float rl = 1.f / lsc[w * 32 + s * 16 + c];
            int rowg = row0 + w * 32 + s * 16 + c;
            float4 res = { acc[s][0] * rl, acc[s][1] * rl,
                           acc[s][2] * rl, acc[s][3] * rl };
            *(float4*)&o[(b0 * 1024 + rowg) * 64 + h * 4] = res;
        }
    }
}

// ---------------- Kernel D: o @ w_proj + BN + max-unpool scatter ----------------
__global__ __launch_bounds__(256) void proj_kernel(const float* __restrict__ o,
                                                   const float* __restrict__ w_proj,
                                                   const float* __restrict__ gamma,
                                                   const float* __restrict__ beta,
                                                   const float* __restrict__ mean,
                                                   const float* __restrict__ var,
                                                   const int* __restrict__ idx,
                                                   float* __restrict__ out) {
    __shared__ float ws[64 * 64];                       // w_proj
    int b = blockIdx.x >> 5, hp = blockIdx.x & 31;
    int tid = threadIdx.x;
    for (int i = tid; i < 4096; i += 256) ws[i] = w_proj[i];
    int wp = tid & 31, cg = tid >> 5;                   // 8 c-groups x 32 wp
    float oreg[64];                                     // my o row in registers
    const float* orow = o + (b * 1024 + hp * 32 + wp) * 64;
    #pragma unroll
    for (int a4 = 0; a4 < 16; a4++) {
        float4 t4 = ((const float4*)orow)[a4];
        oreg[a4 * 4] = t4.x; oreg[a4 * 4 + 1] = t4.y;
        oreg[a4 * 4 + 2] = t4.z; oreg[a4 * 4 + 3] = t4.w;
    }
    __syncthreads();
    #pragma unroll
    for (int g = 0; g < 2; g++) {
        int c0 = cg * 8 + g * 4;                        // 4 consecutive channels
        float4 acc = {0.f, 0.f, 0.f, 0.f};
        #pragma unroll
        for (int a = 0; a < 64; a++) {
            float4 wv = *(const float4*)&ws[a * 64 + c0];   // b128, 2-addr broadcast
            acc.x += oreg[a] * wv.x; acc.y += oreg[a] * wv.y;
            acc.z += oreg[a] * wv.z; acc.w += oreg[a] * wv.w;
        }
        float accs[4] = { acc.x, acc.y, acc.z, acc.w };
        #pragma unroll
        for (int i = 0; i < 4; i++) {
            int c = c0 + i;
            float inv = gamma[c] * rsqrtf(var[c] + 1e-5f);
            float val = accs[i] * inv + (beta[c] - mean[c] * inv);
            int id = idx[((b * 64 + c) * 32 + hp) * 32 + wp];
            int base = ((b * 64 + c) * 64 + 2 * hp) * 64 + 2 * wp;
            float2 r0 = { id == 0 ? val : 0.f, id == 1 ? val : 0.f };
            float2 r1 = { id == 2 ? val : 0.f, id == 3 ? val : 0.f };
            *(float2*)&out[base] = r0;                  // row 2hp,   cols 2wp..2wp+1
            *(float2*)&out[base + 64] = r1;             // row 2hp+1
        }
    }
}

extern "C" void kernel_launch(void* const* d_in, const int* in_sizes, int n_in,
                              void* d_out, int out_size, void* d_ws, size_t ws_size,
                              hipStream_t stream) {
    const float* x      = (const float*)d_in[0];
    const float* w_qkv  = (const float*)d_in[1];
    const float* w_proj = (const float*)d_in[2];
    const float* gamma  = (const float*)d_in[3];
    const float* beta   = (const float*)d_in[4];
    const float* bn_mean= (const float*)d_in[5];
    const float* bn_var = (const float*)d_in[6];
    float* out = (float*)d_out;

    const int SEG = 524288;                             // 8*1024*64
    float* ws = (float*)d_ws;
    float* t   = ws;
    int*   idx = (int*)(ws + SEG);
    float* q   = ws + 2 * SEG;
    float* k   = ws + 3 * SEG;
    float* v   = ws + 4 * SEG;
    float* o   = ws + 5 * SEG;

    pool_kernel<<<2048, 256, 0, stream>>>(x, t, idx);
    qkv_kernel<<<512, 192, 0, stream>>>(t, w_qkv, q, k, v);
    attn_kernel<<<1024, 256, 0, stream>>>(q, k, v, o);
    proj_kernel<<<256, 256, 0, stream>>>(o, w_proj, gamma, beta, bn_mean, bn_var, idx, out);
}

// Round 19
// 118.024 us; speedup vs baseline: 1.1478x; 1.0089x over previous
//
#include <hip/hip_runtime.h>
#include <hip/hip_bf16.h>

// Problem: B=8, C=DIM=64, H=W=64 -> pooled 32x32 (N=1024 tokens), 16 heads x d=4.
// ws layout (floats): t[SEG] | idx[SEG ints] | q[SEG] | k[SEG] | v[SEG] | o[SEG]
//                     | kg[SEG]  (K Markidis f16x8, 16KB/bh)
//                     | vg[SEG/2] (V^T permuted f16, 4x520 u32 rows/bh)
// q/k/v layout: (B, H=16, N=1024, D=4) contiguous -> per (b,h) a 4096-float slab.

typedef float    f32x4 __attribute__((ext_vector_type(4)));
typedef _Float16 f16x8 __attribute__((ext_vector_type(8)));
typedef unsigned int uint32_tt;

static __device__ __forceinline__ uint32_tt pk2(float a, float b) {   // RTN f16 pair
    uint32_tt lo = (uint32_tt)__builtin_bit_cast(unsigned short, (_Float16)a);
    uint32_tt hi = (uint32_tt)__builtin_bit_cast(unsigned short, (_Float16)b);
    return lo | (hi << 16);
}

// ---------------- Kernel A: 2x2 maxpool + argmax ----------------
__global__ __launch_bounds__(256) void pool_kernel(const float* __restrict__ x,
                                                   float* __restrict__ t,
                                                   int* __restrict__ idx) {
    int g = blockIdx.x * 256 + threadIdx.x;            // covers 8*64*32*32 = 524288
    int wp = g & 31, hp = (g >> 5) & 31, c = (g >> 10) & 63, b = g >> 16;
    const float* px = x + (((b * 64 + c) * 64 + 2 * hp) * 64 + 2 * wp);
    float2 r0 = *(const float2*)px;
    float2 r1 = *(const float2*)(px + 64);
    float best = r0.x; int bi = 0;                      // first-max semantics (strict >)
    if (r0.y > best) { best = r0.y; bi = 1; }
    if (r1.x > best) { best = r1.x; bi = 2; }
    if (r1.y > best) { best = r1.y; bi = 3; }
    int n = hp * 32 + wp;
    t[(b * 1024 + n) * 64 + c] = best;
    idx[g] = bi;                                        // layout (b,c,hp,wp)
}

// ---------------- Kernel B: qkv = t @ w_qkv, scatter to (B,H,N,4) ----------------
__global__ __launch_bounds__(192) void qkv_kernel(const float* __restrict__ t,
                                                  const float* __restrict__ w_qkv,
                                                  float* __restrict__ q,
                                                  float* __restrict__ k,
                                                  float* __restrict__ v) {
    __shared__ float trow[16 * 64];                     // 16 token rows
    int tid = threadIdx.x;                              // 0..191
    int row0 = blockIdx.x * 16;
    for (int i = tid; i < 1024; i += 192) trow[i] = t[row0 * 64 + i];
    int j  = tid % 96;                                  // my column pair {j, j+96}
    int rh = tid / 96;                                  // my row half (8 rows)
    float wc0[64], wc1[64];
    #pragma unroll
    for (int c = 0; c < 64; c++) {
        wc0[c] = w_qkv[c * 192 + j];
        wc1[c] = w_qkv[c * 192 + j + 96];
    }
    __syncthreads();
    int s0 = j >> 6, h0 = (j >> 2) & 15, d0 = j & 3;
    int j1 = j + 96;
    int s1 = j1 >> 6, h1 = (j1 >> 2) & 15, d1 = j1 & 3;
    float* dst0 = (s0 == 0) ? q : (s0 == 1) ? k : v;
    float* dst1 = (s1 == 0) ? q : (s1 == 1) ? k : v;
    for (int r = 0; r < 8; r++) {
        int row = rh * 8 + r;
        const float4* tr = (const float4*)&trow[row * 64];
        float a0 = 0.f, a1 = 0.f;
        #pragma unroll
        for (int c4 = 0; c4 < 16; c4++) {
            float4 tv = tr[c4];                         // <=2-way LDS broadcast: free
            a0 += tv.x * wc0[c4 * 4] + tv.y * wc0[c4 * 4 + 1]
                + tv.z * wc0[c4 * 4 + 2] + tv.w * wc0[c4 * 4 + 3];
            a1 += tv.x * wc1[c4 * 4] + tv.y * wc1[c4 * 4 + 1]
                + tv.z * wc1[c4 * 4 + 2] + tv.w * wc1[c4 * 4 + 3];
        }
        int ng = row0 + row, b = ng >> 10, n = ng & 1023;
        dst0[((b * 16 + h0) * 1024 + n) * 4 + d0] = a0;
        dst1[((b * 16 + h1) * 1024 + n) * 4 + d1] = a1;
    }
}

// ---------------- Kernel B2: K/V prep (once per bh, coalesced) ----------------------
// Writes the exact bit patterns attn used to build per-block: K Markidis {hi4|lo4}
// f16x8 per key; V^T permuted f16 rows (pos = kappa(key), pairs packed as u32, RTN).
// Removes the 8x-redundant per-attn-block conversion staging.
__global__ __launch_bounds__(256) void prep_kernel(const float* __restrict__ k,
                                                   const float* __restrict__ v,
                                                   uint4* __restrict__ kg,
                                                   uint32_tt* __restrict__ vg) {
    int bh = blockIdx.x;
    int tid = threadIdx.x;
    const float4* kp4 = (const float4*)(k + bh * 4096);
    const float4* vp4 = (const float4*)(v + bh * 4096);
    uint4* kgb = kg + bh * 1024;
    uint32_tt* vgb = vg + bh * 2080;                    // 4 rows x 520 u32
    #pragma unroll
    for (int i = 0; i < 4; i++) {
        int key = i * 256 + tid;
        float4 kf = kp4[key];
        f16x8 kk;
        kk[0] = (_Float16)kf.x; kk[4] = (_Float16)(kf.x - (float)kk[0]);
        kk[1] = (_Float16)kf.y; kk[5] = (_Float16)(kf.y - (float)kk[1]);
        kk[2] = (_Float16)kf.z; kk[6] = (_Float16)(kf.z - (float)kk[2]);
        kk[3] = (_Float16)kf.w; kk[7] = (_Float16)(kf.w - (float)kk[3]);
        kgb[key] = __builtin_bit_cast(uint4, kk);       // fully coalesced 16B
    }
    #pragma unroll
    for (int i = 0; i < 2; i++) {
        int m = i * 256 + tid;                          // pair index (512 pairs)
        int key = 2 * m;                                // even key: pos(key+1)=pos+1
        float4 v0 = vp4[key], v1 = vp4[key + 1];
        int pos = (key & ~31) | (((key & 15) >> 2) << 3)
                | (((key >> 4) & 1) << 2) | (key & 3);  // kappa (bijective, even)
        int pw = pos >> 1;
        vgb[0 * 520 + pw] = pk2(v0.x, v1.x);            // coalesced u32 within 256B
        vgb[1 * 520 + pw] = pk2(v0.y, v1.y);
        vgb[2 * 520 + pw] = pk2(v0.z, v1.z);
        vgb[3 * 520 + pw] = pk2(v0.w, v1.w);
    }
}

// ---------------- Kernel C: dual-MFMA attention, 32-key tile-pairs ------------------
// R18 post-mortem: occupancy doubling underdelivered -- suspects: VGPR >128 (no pin)
// and doubled redundant staging. R19: staging = pure uint4 copies from prep_kernel's
// global buffers (+local ones-row), and __launch_bounds__(256,4) pins VGPR <=128 so
// 4 waves/SIMD actually materialize. Loop body & scheme frozen (R15-R18-proven):
//  MFMA1: S^T-14 = K x Q^T + C(-14).  A = {kh|kl} Markidis (lane m=key); B = Q
//         Markidis (quad0={qh|qh}, quad1={ql|ql}) -> fp32-exact S. C row=quad*4+reg.
//  MFMA2: O^T = V^T x P^T over 32 keys/instr: V plain f16, kappa-permuted layout;
//         ones-row m=4 emits l = sum(p); exp2(S-14) cancels in O/l; P via v_cvt_pkrtz.
// grid = 128 bh * 8 row-blocks of 128; block = 4 waves, wave = 2 strips of 16 rows.
__global__ __launch_bounds__(256, 4) void attn_kernel(const float* __restrict__ q,
                                                      const uint4* __restrict__ kg,
                                                      const uint32_tt* __restrict__ vg,
                                                      float* __restrict__ o) {
    __shared__ __align__(16) unsigned char smem[27840];
    f16x8* Kh2 = (f16x8*)smem;                          // [0,16384): 1024 keys {hi4|lo4}
    // VTu rows at smem+16384, stride 2080 B; rows 0-3 copied, row 4 = ones (local)
    float* lsc = (float*)(smem + 26752);                // l exchange (1 KB)
    int bh = blockIdx.x >> 3;
    int row0 = (blockIdx.x & 7) * 128;
    int tid = threadIdx.x;
    uint4* smem4 = (uint4*)smem;
    const uint4* kgb = kg + bh * 1024;
    const uint4* vgb = (const uint4*)(vg + bh * 2080);
    #pragma unroll
    for (int i = 0; i < 4; i++)                         // K: 16 KB raw copy
        smem4[i * 256 + tid] = kgb[i * 256 + tid];
    #pragma unroll
    for (int i = 0; i < 3; i++) {                       // V rows 0-3: 8320 B raw copy
        int ix = i * 256 + tid;
        if (ix < 520) smem4[1024 + ix] = vgb[ix];
    }
    {                                                   // ones row: 2 KB of f16 1.0
        uint32_tt* op = (uint32_tt*)(smem + 24704);
        op[tid] = 0x3C003C00u;
        op[256 + tid] = 0x3C003C00u;
    }
    int w = tid >> 6, lane = tid & 63;
    int c = lane & 15, quad = lane >> 4;
    int mv = (c < 5) ? c : 4;                           // clamp -> broadcast ones-row
    const float C1 = 0.5f * 1.44269504088896f;          // scale*log2(e), folded into Q
    const float4* qp4 = (const float4*)(q + bh * 4096);
    f16x8 bq[2];
    #pragma unroll
    for (int s = 0; s < 2; s++) {                       // Q Markidis B-frags (2 strips)
        int rowg = row0 + w * 32 + s * 16 + c;
        float4 qv = qp4[rowg];
        float qx = qv.x * C1, qy = qv.y * C1, qz = qv.z * C1, qw = qv.w * C1;
        _Float16 hx = (_Float16)qx, hy = (_Float16)qy,
                 hz = (_Float16)qz, hw = (_Float16)qw;
        _Float16 gx = (_Float16)(qx - (float)hx), gy = (_Float16)(qy - (float)hy),
                 gz = (_Float16)(qz - (float)hz), gw = (_Float16)(qw - (float)hw);
        f16x8 a = {};
        if (quad == 0) {
            a[0] = hx; a[1] = hy; a[2] = hz; a[3] = hw;
            a[4] = hx; a[5] = hy; a[6] = hz; a[7] = hw;
        } else if (quad == 1) {
            a[0] = gx; a[1] = gy; a[2] = gz; a[3] = gw;
            a[4] = gx; a[5] = gy; a[6] = gz; a[7] = gw;
        }
        bq[s] = a;
    }
    __syncthreads();
    f32x4 acc[2];
    acc[0] = (f32x4)(0.f); acc[1] = (f32x4)(0.f);
    const f32x4 cm14 = { -14.f, -14.f, -14.f, -14.f }; // shift rides in MFMA1's C
    #pragma unroll 2
    for (int T = 0; T < 32; T++) {                      // 32-key tile-pairs
        f16x8 ka0 = Kh2[(2 * T) * 16 + c];              // ds_read_b128 (broadcast)
        f16x8 ka1 = Kh2[(2 * T + 1) * 16 + c];
        const uint4* vptr = (const uint4*)(smem + 16384
                                           + mv * 2080 + T * 64 + quad * 16);
        f16x8 va = __builtin_bit_cast(f16x8, *vptr);    // V^T A-frag: 32 keys, 1 read
        #pragma unroll
        for (int s = 0; s < 2; s++) {
            f32x4 S0 = __builtin_amdgcn_mfma_f32_16x16x32_f16(ka0, bq[s], cm14, 0, 0, 0);
            f32x4 S1 = __builtin_amdgcn_mfma_f32_16x16x32_f16(ka1, bq[s], cm14, 0, 0, 0);
            float p00 = __builtin_amdgcn_exp2f(S0[0]);  // bare v_exp_f32 (trans pipe)
            float p01 = __builtin_amdgcn_exp2f(S0[1]);
            float p02 = __builtin_amdgcn_exp2f(S0[2]);
            float p03 = __builtin_amdgcn_exp2f(S0[3]);
            float p10 = __builtin_amdgcn_exp2f(S1[0]);
            float p11 = __builtin_amdgcn_exp2f(S1[1]);
            float p12 = __builtin_amdgcn_exp2f(S1[2]);
            float p13 = __builtin_amdgcn_exp2f(S1[3]);
            uint4 pbu;                                  // v_cvt_pkrtz: 2 converts/instr
            pbu.x = __builtin_bit_cast(uint32_tt, __builtin_amdgcn_cvt_pkrtz(p00, p01));
            pbu.y = __builtin_bit_cast(uint32_tt, __builtin_amdgcn_cvt_pkrtz(p02, p03));
            pbu.z = __builtin_bit_cast(uint32_tt, __builtin_amdgcn_cvt_pkrtz(p10, p11));
            pbu.w = __builtin_bit_cast(uint32_tt, __builtin_amdgcn_cvt_pkrtz(p12, p13));
            f16x8 pb = __builtin_bit_cast(f16x8, pbu);
            acc[s] = __builtin_amdgcn_mfma_f32_16x16x32_f16(va, pb, acc[s], 0, 0, 0);
        }
    }
    // Epilogue: quad1 reg0 holds l (row 4 = ones-row); quad0 regs 0-3 hold O dims.
    if (quad == 1) {
        #pragma unroll
        for (int s = 0; s < 2; s++) lsc[w * 32 + s * 16 + c] = acc[s][0];
    }
    __syncthreads();
    if (quad == 0) {
        int b0 = bh >> 4, h = bh & 15;
        #pragma unroll
        for (int s = 0; s < 2; s++) {
            float rl = 1.f / lsc[w * 32 + s * 16 + c];
            int rowg = row0 + w * 32 + s * 16 + c;
            float4 res = { acc[s][0] * rl, acc[s][1] * rl,
                           acc[s][2] * rl, acc[s][3] * rl };
            *(float4*)&o[(b0 * 1024 + rowg) * 64 + h * 4] = res;
        }
    }
}

// ---------------- Kernel D: o @ w_proj + BN + max-unpool scatter ----------------
__global__ __launch_bounds__(256) void proj_kernel(const float* __restrict__ o,
                                                   const float* __restrict__ w_proj,
                                                   const float* __restrict__ gamma,
                                                   const float* __restrict__ beta,
                                                   const float* __restrict__ mean,
                                                   const float* __restrict__ var,
                                                   const int* __restrict__ idx,
                                                   float* __restrict__ out) {
    __shared__ float ws[64 * 64];                       // w_proj
    int b = blockIdx.x >> 5, hp = blockIdx.x & 31;
    int tid = threadIdx.x;
    for (int i = tid; i < 4096; i += 256) ws[i] = w_proj[i];
    int wp = tid & 31, cg = tid >> 5;                   // 8 c-groups x 32 wp
    float oreg[64];                                     // my o row in registers
    const float* orow = o + (b * 1024 + hp * 32 + wp) * 64;
    #pragma unroll
    for (int a4 = 0; a4 < 16; a4++) {
        float4 t4 = ((const float4*)orow)[a4];
        oreg[a4 * 4] = t4.x; oreg[a4 * 4 + 1] = t4.y;
        oreg[a4 * 4 + 2] = t4.z; oreg[a4 * 4 + 3] = t4.w;
    }
    __syncthreads();
    #pragma unroll
    for (int g = 0; g < 2; g++) {
        int c0 = cg * 8 + g * 4;                        // 4 consecutive channels
        float4 acc = {0.f, 0.f, 0.f, 0.f};
        #pragma unroll
        for (int a = 0; a < 64; a++) {
            float4 wv = *(const float4*)&ws[a * 64 + c0];   // b128, 2-addr broadcast
            acc.x += oreg[a] * wv.x; acc.y += oreg[a] * wv.y;
            acc.z += oreg[a] * wv.z; acc.w += oreg[a] * wv.w;
        }
        float accs[4] = { acc.x, acc.y, acc.z, acc.w };
        #pragma unroll
        for (int i = 0; i < 4; i++) {
            int c = c0 + i;
            float inv = gamma[c] * rsqrtf(var[c] + 1e-5f);
            float val = accs[i] * inv + (beta[c] - mean[c] * inv);
            int id = idx[((b * 64 + c) * 32 + hp) * 32 + wp];
            int base = ((b * 64 + c) * 64 + 2 * hp) * 64 + 2 * wp;
            float2 r0 = { id == 0 ? val : 0.f, id == 1 ? val : 0.f };
            float2 r1 = { id == 2 ? val : 0.f, id == 3 ? val : 0.f };
            *(float2*)&out[base] = r0;                  // row 2hp,   cols 2wp..2wp+1
            *(float2*)&out[base + 64] = r1;             // row 2hp+1
        }
    }
}

extern "C" void kernel_launch(void* const* d_in, const int* in_sizes, int n_in,
                              void* d_out, int out_size, void* d_ws, size_t ws_size,
                              hipStream_t stream) {
    const float* x      = (const float*)d_in[0];
    const float* w_qkv  = (const float*)d_in[1];
    const float* w_proj = (const float*)d_in[2];
    const float* gamma  = (const float*)d_in[3];
    const float* beta   = (const float*)d_in[4];
    const float* bn_mean= (const float*)d_in[5];
    const float* bn_var = (const float*)d_in[6];
    float* out = (float*)d_out;

    const int SEG = 524288;                             // 8*1024*64
    float* ws = (float*)d_ws;
    float* t   = ws;
    int*   idx = (int*)(ws + SEG);
    float* q   = ws + 2 * SEG;
    float* k   = ws + 3 * SEG;
    float* v   = ws + 4 * SEG;
    float* o   = ws + 5 * SEG;
    uint4*     kg = (uint4*)(ws + 6 * SEG);             // 2 MB
    uint32_tt* vg = (uint32_tt*)(ws + 7 * SEG);         // 1.04 MB

    pool_kernel<<<2048, 256, 0, stream>>>(x, t, idx);
    qkv_kernel<<<512, 192, 0, stream>>>(t, w_qkv, q, k, v);
    prep_kernel<<<128, 256, 0, stream>>>(k, v, kg, vg);
    attn_kernel<<<1024, 256, 0, stream>>>(q, kg, vg, o);
    proj_kernel<<<256, 256, 0, stream>>>(o, w_proj, gamma, beta, bn_mean, bn_var, idx, out);
}